// Round 2
// baseline (3193.376 us; speedup 1.0000x reference)
//
#include <hip/hip_runtime.h>
#include <stdint.h>

#define B_ 16
#define N_ 2048
#define C_ 1024

using u16 = unsigned short;
typedef __attribute__((ext_vector_type(4))) float f32x4;
typedef __attribute__((ext_vector_type(8))) short s16x8;
typedef __attribute__((ext_vector_type(8))) unsigned short u16x8;
typedef __attribute__((ext_vector_type(4))) unsigned short u16x4;

static __device__ __forceinline__ float bf2f(u16 u) {
  union { unsigned int i; float f; } c; c.i = ((unsigned int)u) << 16; return c.f;
}
static __device__ __forceinline__ u16 f2bf(float f) {
  union { float f; unsigned int i; } c; c.f = f;
  unsigned int r = c.i + 0x7FFFu + ((c.i >> 16) & 1u);
  return (u16)(r >> 16);
}

// ---------------- f32 -> bf16 convert (grid-stride, 4/thread) ----------------
__global__ void cvt_bf16_kernel(const float* __restrict__ in, u16* __restrict__ out, long n)
{
  long i = ((long)blockIdx.x * blockDim.x + threadIdx.x) * 4;
  const long stride = (long)gridDim.x * blockDim.x * 4;
  for (; i < n; i += stride) {
    float4 v = *(const float4*)(in + i);
    u16x4 o; o.x = f2bf(v.x); o.y = f2bf(v.y); o.z = f2bf(v.z); o.w = f2bf(v.w);
    *(u16x4*)(out + i) = o;
  }
}

// ---------------- LayerNorm over C=1024, out bf16 ----------------
__global__ __launch_bounds__(256)
void ln_kernel(const float* __restrict__ x, const float* __restrict__ g,
               const float* __restrict__ bb, u16* __restrict__ out)
{
  __shared__ float rs[4], rs2[4];
  const long r = blockIdx.x;
  const float* xr = x + r * C_;
  const int t = threadIdx.x;
  float4 v = ((const float4*)xr)[t];
  float s  = v.x + v.y + v.z + v.w;
  float s2 = v.x * v.x + v.y * v.y + v.z * v.z + v.w * v.w;
  #pragma unroll
  for (int o = 32; o > 0; o >>= 1) { s += __shfl_xor(s, o); s2 += __shfl_xor(s2, o); }
  const int lane = t & 63, wv = t >> 6;
  if (lane == 0) { rs[wv] = s; rs2[wv] = s2; }
  __syncthreads();
  s  = rs[0] + rs[1] + rs[2] + rs[3];
  s2 = rs2[0] + rs2[1] + rs2[2] + rs2[3];
  const float mean = s * (1.f / C_);
  const float var  = s2 * (1.f / C_) - mean * mean;
  const float inv  = rsqrtf(var + 1e-5f);
  float4 gv = ((const float4*)g)[t];
  float4 bv = ((const float4*)bb)[t];
  u16x4 o;
  o.x = f2bf((v.x - mean) * inv * gv.x + bv.x);
  o.y = f2bf((v.y - mean) * inv * gv.y + bv.y);
  o.z = f2bf((v.z - mean) * inv * gv.z + bv.z);
  o.w = f2bf((v.w - mean) * inv * gv.w + bv.w);
  *(u16x4*)(out + r * C_ + t * 4) = o;
}

// ---------------- GEMM: C[M,N] = A[M,K] @ B^T (B stored [N,K]) -----------------
// 128x128 tile, BK=32, 4 waves (2x2), mfma_f32_16x16x32_bf16, global_load_lds.
// Epilogue: *scale, +bias[col], relu, +res (fp32, same indexing as C), out bf16/f32.
template<bool OUT_BF16, bool HAS_BIAS, bool HAS_RES, bool RELU>
__global__ __launch_bounds__(256)
void gemm_bt(const u16* __restrict__ A, const u16* __restrict__ Bm,
             const float* __restrict__ bias, const float* res,
             void* Cout, int K, int lda, int ldb, int ldc,
             long sA, long sB, long sC, float scale)
{
  __shared__ u16 As[128 * 32];
  __shared__ u16 Bs[128 * 32];
  const int bz = blockIdx.z;
  A  += (long)bz * sA;
  Bm += (long)bz * sB;
  const long coff = (long)bz * sC;
  const int bn0 = blockIdx.x * 128;
  const int bm0 = blockIdx.y * 128;
  const int tid = threadIdx.x;
  const int wave = tid >> 6, lane = tid & 63;
  const int wr = wave >> 1, wc = wave & 1;

  f32x4 acc[4][4] = {};

  // staging: 8 chunks of 16 rows x 32 cols (1024B each); wave handles chunks 2w,2w+1
  const int srow = lane >> 2;          // 16 rows per chunk, 4 lanes/row
  const int scol = (lane & 3) * 8;     // 8 bf16 = 16B per lane
  const int c0 = wave * 2, c1 = c0 + 1;
  const u16* ga0 = A  + (long)(bm0 + c0 * 16 + srow) * lda + scol;
  const u16* ga1 = A  + (long)(bm0 + c1 * 16 + srow) * lda + scol;
  const u16* gb0 = Bm + (long)(bn0 + c0 * 16 + srow) * ldb + scol;
  const u16* gb1 = Bm + (long)(bn0 + c1 * 16 + srow) * ldb + scol;
  u16* lA0 = As + c0 * 512;  // wave-uniform LDS bases (HW adds lane*16B)
  u16* lA1 = As + c1 * 512;
  u16* lB0 = Bs + c0 * 512;
  u16* lB1 = Bs + c1 * 512;

  for (int k0 = 0; k0 < K; k0 += 32) {
    __builtin_amdgcn_global_load_lds((const __attribute__((address_space(1))) void*)(ga0 + k0),
                                     (__attribute__((address_space(3))) void*)lA0, 16, 0, 0);
    __builtin_amdgcn_global_load_lds((const __attribute__((address_space(1))) void*)(ga1 + k0),
                                     (__attribute__((address_space(3))) void*)lA1, 16, 0, 0);
    __builtin_amdgcn_global_load_lds((const __attribute__((address_space(1))) void*)(gb0 + k0),
                                     (__attribute__((address_space(3))) void*)lB0, 16, 0, 0);
    __builtin_amdgcn_global_load_lds((const __attribute__((address_space(1))) void*)(gb1 + k0),
                                     (__attribute__((address_space(3))) void*)lB1, 16, 0, 0);
    __syncthreads();
    const int frow = lane & 15;
    const int fkb  = (lane >> 4) * 8;
    s16x8 af[4], bfv[4];
    #pragma unroll
    for (int m = 0; m < 4; ++m)
      af[m] = *(const s16x8*)(As + (wr * 64 + m * 16 + frow) * 32 + fkb);
    #pragma unroll
    for (int n = 0; n < 4; ++n)
      bfv[n] = *(const s16x8*)(Bs + (wc * 64 + n * 16 + frow) * 32 + fkb);
    #pragma unroll
    for (int m = 0; m < 4; ++m)
      #pragma unroll
      for (int n = 0; n < 4; ++n)
        acc[m][n] = __builtin_amdgcn_mfma_f32_16x16x32_bf16(af[m], bfv[n], acc[m][n], 0, 0, 0);
    __syncthreads();
  }

  // epilogue: D layout col = lane&15, row = (lane>>4)*4 + j
  const int colq = lane & 15;
  const int rowq = (lane >> 4) * 4;
  #pragma unroll
  for (int m = 0; m < 4; ++m) {
    #pragma unroll
    for (int n = 0; n < 4; ++n) {
      const int col = bn0 + wc * 64 + n * 16 + colq;
      const float bvv = HAS_BIAS ? bias[col] : 0.f;
      #pragma unroll
      for (int j = 0; j < 4; ++j) {
        const int row = bm0 + wr * 64 + m * 16 + rowq + j;
        float v = acc[m][n][j] * scale + bvv;
        if (RELU) v = fmaxf(v, 0.f);
        const long idx = coff + (long)row * ldc + col;
        if (HAS_RES) v += res[idx];
        if (OUT_BF16) ((u16*)Cout)[idx] = f2bf(v);
        else          ((float*)Cout)[idx] = v;
      }
    }
  }
}

// ---------------- self-attention over sequence axis B=16 ----------------
// one block per (n, h); Q,K,V are [16][64] slices of qkv [i*N+n][3C]
__global__ __launch_bounds__(256)
void attn_self_kernel(const u16* __restrict__ qkv, u16* __restrict__ sa)
{
  __shared__ float Q[16][65], Kk[16][65], V[16][65], P[16][17];
  const int bid = blockIdx.x;
  const int n = bid >> 4, h = bid & 15;
  const int t = threadIdx.x;
  for (int e = t; e < 1024; e += 256) {
    const int i = e >> 6, d = e & 63;
    const long base = ((long)i * N_ + n) * (3 * C_) + h * 64 + d;
    Q[i][d]  = bf2f(qkv[base]);
    Kk[i][d] = bf2f(qkv[base + C_]);
    V[i][d]  = bf2f(qkv[base + 2 * C_]);
  }
  __syncthreads();
  const int i = t >> 4, j = t & 15;
  float s = 0.f;
  #pragma unroll
  for (int d = 0; d < 64; ++d) s += Q[i][d] * Kk[j][d];
  s *= 0.125f;  // 1/sqrt(64)
  float mx = s;
  #pragma unroll
  for (int o = 8; o > 0; o >>= 1) mx = fmaxf(mx, __shfl_xor(mx, o, 16));
  const float p = expf(s - mx);
  float sum = p;
  #pragma unroll
  for (int o = 8; o > 0; o >>= 1) sum += __shfl_xor(sum, o, 16);
  P[i][j] = p / sum;
  __syncthreads();
  const int d0 = (t & 15) * 4;
  float o0 = 0, o1 = 0, o2 = 0, o3 = 0;
  #pragma unroll
  for (int jj = 0; jj < 16; ++jj) {
    const float a = P[i][jj];
    o0 += a * V[jj][d0]; o1 += a * V[jj][d0 + 1]; o2 += a * V[jj][d0 + 2]; o3 += a * V[jj][d0 + 3];
  }
  u16x4 o; o.x = f2bf(o0); o.y = f2bf(o1); o.z = f2bf(o2); o.w = f2bf(o3);
  *(u16x4*)(sa + ((long)i * N_ + n) * C_ + h * 64 + d0) = o;
}

// ---------------- row softmax (2048 cols, bf16, in place) ----------------
__global__ __launch_bounds__(256)
void softmax_rows_kernel(u16* __restrict__ s)
{
  __shared__ float red[4], red2[4];
  const long r = blockIdx.x;
  u16* row = s + r * 2048;
  const int t = threadIdx.x;
  u16x8 u = ((u16x8*)row)[t];
  float f[8];
  #pragma unroll
  for (int k = 0; k < 8; ++k) f[k] = bf2f(u[k]);
  float mx = f[0];
  #pragma unroll
  for (int k = 1; k < 8; ++k) mx = fmaxf(mx, f[k]);
  #pragma unroll
  for (int o = 32; o > 0; o >>= 1) mx = fmaxf(mx, __shfl_xor(mx, o));
  if ((t & 63) == 0) red[t >> 6] = mx;
  __syncthreads();
  mx = fmaxf(fmaxf(red[0], red[1]), fmaxf(red[2], red[3]));
  float sum = 0.f;
  #pragma unroll
  for (int k = 0; k < 8; ++k) { f[k] = expf(f[k] - mx); sum += f[k]; }
  #pragma unroll
  for (int o = 32; o > 0; o >>= 1) sum += __shfl_xor(sum, o);
  if ((t & 63) == 0) red2[t >> 6] = sum;
  __syncthreads();
  const float inv = 1.f / (red2[0] + red2[1] + red2[2] + red2[3]);
  #pragma unroll
  for (int k = 0; k < 8; ++k) u[k] = f2bf(f[k] * inv);
  ((u16x8*)row)[t] = u;
}

// ---------------- transpose vc: vct[b][n][j] = kv[b][j][1024+n] ----------------
__global__ __launch_bounds__(256)
void transpose_vc_kernel(const u16* __restrict__ kv, u16* __restrict__ vct)
{
  __shared__ u16 tile[32][33];
  const int b = blockIdx.z;
  const int jt = blockIdx.x * 32, nt = blockIdx.y * 32;
  const int tx = threadIdx.x & 31, ty = threadIdx.x >> 5;
  #pragma unroll
  for (int k = 0; k < 4; ++k) {
    const int j = jt + ty + k * 8;
    tile[ty + k * 8][tx] = kv[((long)b * N_ + j) * 2048 + 1024 + nt + tx];
  }
  __syncthreads();
  #pragma unroll
  for (int k = 0; k < 4; ++k) {
    const int nn = nt + ty + k * 8;
    vct[((long)b * 1024 + nn) * 2048 + jt + tx] = tile[tx][ty + k * 8];
  }
}

extern "C" void kernel_launch(void* const* d_in, const int* in_sizes, int n_in,
                              void* d_out, int out_size, void* d_ws, size_t ws_size,
                              hipStream_t stream)
{
  const float* x        = (const float*)d_in[0];
  const float* ctx      = (const float*)d_in[1];
  const float* ln_g     = (const float*)d_in[2];
  const float* ln_b     = (const float*)d_in[3];
  const float* in_proj_w= (const float*)d_in[4];
  const float* in_proj_b= (const float*)d_in[5];
  const float* out_w    = (const float*)d_in[6];
  const float* out_b    = (const float*)d_in[7];
  const float* q_w      = (const float*)d_in[8];
  const float* q_b      = (const float*)d_in[9];
  const float* kv_w     = (const float*)d_in[10];
  const float* kv_b     = (const float*)d_in[11];
  const float* ff1_w    = (const float*)d_in[12];
  const float* ff1_b    = (const float*)d_in[13];
  const float* ff2_w    = (const float*)d_in[14];
  const float* ff2_b    = (const float*)d_in[15];

  char* ws = (char*)d_ws;
  const size_t MB = 1u << 20;
  // bf16 weights at [0, 36MB)
  u16* w_inproj = (u16*)ws;
  u16* w_out = w_inproj + 3145728;
  u16* w_q   = w_out + 1048576;
  u16* w_kv  = w_q + 1048576;
  u16* w_ff1 = w_kv + 4194304;
  u16* w_ff2 = w_ff1 + 4194304;
  // activation arena (reused across phases); peak need ~652 MiB
  u16*  h    = (u16*)(ws + 40 * MB);    // 64MB  bf16 [32768,1024]
  float* x1  = (float*)(ws + 112 * MB); // 128MB f32  [32768,1024] (x after residuals)
  u16*  qkv  = (u16*)(ws + 252 * MB);   // 192MB bf16 [32768,3072]
  u16*  sa   = (u16*)(ws + 466 * MB);   // 64MB  bf16 [32768,1024]
  u16*  kvb  = (u16*)(ws + 252 * MB);   // 128MB bf16 [16,2048,2048] (reuses qkv)
  u16*  ctxb = (u16*)(ws + 388 * MB);   // 128MB bf16 context
  u16*  qc   = (u16*)(ws + 388 * MB);   // 64MB  bf16 (reuses ctxb after kv GEMM)
  u16*  vct  = (u16*)(ws + 456 * MB);   // 64MB  bf16 [16,1024,2048]
  u16*  sc   = (u16*)(ws + 524 * MB);   // 128MB bf16 [16,2048,2048] scores/attn
  u16*  ffo  = (u16*)(ws + 252 * MB);   // 256MB bf16 [32768,4096]

  dim3 blk(256);
  const int R = B_ * N_;  // 32768

  // weights -> bf16
  cvt_bf16_kernel<<<512, blk, 0, stream>>>(in_proj_w, w_inproj, 3145728);
  cvt_bf16_kernel<<<256, blk, 0, stream>>>(out_w, w_out, 1048576);
  cvt_bf16_kernel<<<256, blk, 0, stream>>>(q_w,   w_q,   1048576);
  cvt_bf16_kernel<<<512, blk, 0, stream>>>(kv_w,  w_kv,  4194304);
  cvt_bf16_kernel<<<512, blk, 0, stream>>>(ff1_w, w_ff1, 4194304);
  cvt_bf16_kernel<<<512, blk, 0, stream>>>(ff2_w, w_ff2, 4194304);

  // ---- self-attention block ----
  ln_kernel<<<R, blk, 0, stream>>>(x, ln_g, ln_b, h);
  gemm_bt<true,true,false,false><<<dim3(24, 256, 1), blk, 0, stream>>>(
      h, w_inproj, in_proj_b, nullptr, qkv, 1024, 1024, 1024, 3072, 0, 0, 0, 1.f);
  attn_self_kernel<<<N_ * 16, blk, 0, stream>>>(qkv, sa);
  gemm_bt<false,true,true,false><<<dim3(8, 256, 1), blk, 0, stream>>>(
      sa, w_out, out_b, x, x1, 1024, 1024, 1024, 1024, 0, 0, 0, 1.f);

  // ---- cross-attention block ----
  ln_kernel<<<R, blk, 0, stream>>>(x1, ln_g, ln_b, h);
  cvt_bf16_kernel<<<4096, blk, 0, stream>>>(ctx, ctxb, (long)R * 2048);
  gemm_bt<true,true,false,false><<<dim3(16, 256, 1), blk, 0, stream>>>(
      ctxb, w_kv, kv_b, nullptr, kvb, 2048, 2048, 2048, 2048, 0, 0, 0, 1.f);
  gemm_bt<true,true,false,false><<<dim3(8, 256, 1), blk, 0, stream>>>(
      h, w_q, q_b, nullptr, qc, 1024, 1024, 1024, 1024, 0, 0, 0, 1.f);
  transpose_vc_kernel<<<dim3(64, 32, 16), blk, 0, stream>>>(kvb, vct);
  // scores[b] = qc[b] @ kc[b]^T * C^-0.5
  gemm_bt<true,false,false,false><<<dim3(16, 16, 16), blk, 0, stream>>>(
      qc, kvb, nullptr, nullptr, sc, 1024, 1024, 2048, 2048,
      (long)N_ * 1024, (long)N_ * 2048, (long)N_ * 2048, 0.03125f);
  softmax_rows_kernel<<<R, blk, 0, stream>>>(sc);
  // x1 += attn[b] @ vc[b]
  gemm_bt<false,false,true,false><<<dim3(8, 16, 16), blk, 0, stream>>>(
      sc, vct, nullptr, x1, x1, 2048, 2048, 2048, 1024,
      (long)N_ * 2048, (long)1024 * 2048, (long)N_ * 1024, 1.f);

  // ---- FFN block ----
  ln_kernel<<<R, blk, 0, stream>>>(x1, ln_g, ln_b, h);
  gemm_bt<true,true,false,true><<<dim3(32, 256, 1), blk, 0, stream>>>(
      h, w_ff1, ff1_b, nullptr, ffo, 1024, 1024, 1024, 4096, 0, 0, 0, 1.f);
  gemm_bt<false,true,true,false><<<dim3(8, 256, 1), blk, 0, stream>>>(
      ffo, w_ff2, ff2_b, x1, (float*)d_out, 4096, 4096, 4096, 1024, 0, 0, 0, 1.f);
}